// Round 7
// baseline (255.948 us; speedup 1.0000x reference)
//
#include <hip/hip_runtime.h>

// Sparse conv block, output-major, exch-chain inversion (round 7):
//   init+build (fused): Wt/xb bf16 prep + per-pair atomicExch chain heads
//   compact: chain -> direct gather row (ZROW/single/aux), written TRANSPOSED
//            as bt[o][27] so conv's idx reads are L1-resident
//   fixup: aux rows = bf16 sum of chain inputs
//   conv: 64 rows/block (grid 1564 = 6 blocks/CU), depth-2 row prefetch,
//         W[k] LDS double-buffered + XOR-swizzled, fused BN stats
//   norm: BN+ReLU.                                MI355X / gfx950.

#define N_VOX   100000
#define NPAD    100096                  // multiple of 64
#define K3      27
#define M_PAIRS 40000
#define NPAIRS  (K3 * M_PAIRS)          // 1,080,000
#define BN_EPS  1e-5f
#define NBINS   (K3 * NPAD)             // 2,702,592
#define AUXMAX  172032                  // E[multi bins]=166.4k, +14 sigma headroom
#define AUXCAP  (AUXMAX - 1)
#define ZROW    (N_VOX + AUXMAX - 1)    // zeroed gather row (empty bins)

// ---- workspace layout (bytes), total 55,180,416 -----------------------------
#define OFF_WT     0u                       // bf16 Wt[k][c][i]  (221,184)
#define OFF_STATS  221184u                  // f32[128]
#define OFF_CTRS   221696u                  // [0]=aux counter (+pad to 64B)
#define OFF_BT     221760u                  // int bt[NPAD][27]  (10,810,368)
#define OFF_NODE   11032128u                // int2 node[NPAIRS] (8,640,000)
#define OFF_LIST   19672128u                // int list[AUXMAX]  (688,128)
#define OFF_XB     20360320u                // bf16 rows[N_VOX+AUXMAX][64] (34,820,096)
// chain heads alias xb's AUX region (dead after compact; fixup overwrites):
#define OFF_BH     (OFF_XB + (size_t)N_VOX * 128u)    // NBINS*4 = 10,810,368
#define WS_NEED    ((size_t)OFF_XB + (size_t)(N_VOX + AUXMAX) * 128u)

#define NB_WT    432                    // 27*4096/256
#define NB_XB    3125                   // ceil(N_VOX*8/256)
#define NB_BUILD 4219                   // ceil(NPAIRS/256)
#define GRID_IB  (NB_WT + NB_XB + 1 + NB_BUILD)   // 7777

typedef __attribute__((ext_vector_type(8))) short bf16x8;
typedef __attribute__((ext_vector_type(4))) float f32x4;

__device__ __forceinline__ short f2bf(float f) {
  unsigned u = __builtin_bit_cast(unsigned, f);
  u += 0x7FFFu + ((u >> 16) & 1u);
  return (short)(u >> 16);
}
__device__ __forceinline__ float bf2f(short s) {
  unsigned u = ((unsigned)(unsigned short)s) << 16;
  return __builtin_bit_cast(float, u);
}

// ---- fused init + build -----------------------------------------------------
// blocks [0,NB_WT): W[k][i][c] f32 -> wt[k][c][i] bf16
// blocks [NB_WT, NB_WT+NB_XB): x f32 -> xb bf16
// block NB_WT+NB_XB: zero ZROW
// rest: per pair atomicExch chain insert (heads=-1 preset by memset)
__global__ __launch_bounds__(256) void init_build_kernel(const float* __restrict__ W,
                                                         const float* __restrict__ x,
                                                         const int* __restrict__ in_idx,
                                                         const int* __restrict__ out_idx,
                                                         short* __restrict__ wt,
                                                         short* __restrict__ xb,
                                                         int* __restrict__ bh,
                                                         int2* __restrict__ node) {
  int b = blockIdx.x, t = threadIdx.x;
  if (b < NB_WT) {
    int id = b * 256 + t;
    int k = id >> 12, rem = id & 4095, c = rem >> 6, i = rem & 63;
    wt[id] = f2bf(W[(k << 12) + (i << 6) + c]);
  } else if (b < NB_WT + NB_XB) {
    int id = (b - NB_WT) * 256 + t;
    if (id < N_VOX * 8) {
      float4 lo = ((const float4*)x)[id * 2];
      float4 hi = ((const float4*)x)[id * 2 + 1];
      bf16x8 v;
      v[0] = f2bf(lo.x); v[1] = f2bf(lo.y); v[2] = f2bf(lo.z); v[3] = f2bf(lo.w);
      v[4] = f2bf(hi.x); v[5] = f2bf(hi.y); v[6] = f2bf(hi.z); v[7] = f2bf(hi.w);
      ((bf16x8*)xb)[id] = v;
    }
  } else if (b == NB_WT + NB_XB) {
    if (t < 8) {
      bf16x8 z = {0, 0, 0, 0, 0, 0, 0, 0};
      ((bf16x8*)(xb + (size_t)ZROW * 64))[t] = z;
    }
  } else {
    int id = (b - (NB_WT + NB_XB + 1)) * 256 + t;
    if (id < NPAIRS) {
      int k  = id / M_PAIRS;
      int in = in_idx[id];
      int o  = out_idx[id];
      int bb = k * NPAD + o;
      int old = atomicExch(&bh[bb], id);
      node[id] = make_int2(old, in);
    }
  }
}

// ---- compact: head -> gather row, written transposed bt[o][27] --------------
//   empty -> ZROW ; single -> input row ; multi -> N_VOX + aux slot
__global__ __launch_bounds__(256) void compact_kernel(const int* __restrict__ bh,
                                                      const int2* __restrict__ node,
                                                      int* __restrict__ bt,
                                                      int* __restrict__ list,
                                                      int* __restrict__ ctrs) {
  __shared__ int l_cnt, l_base;
  int t = threadIdx.x;
  if (t == 0) l_cnt = 0;
  __syncthreads();
  int w = blockIdx.x * 256 + t;                 // 4 bins per thread
  bool ok = (w < NBINS / 4);
  int4 h4 = ok ? ((const int4*)bh)[w] : make_int4(-1, -1, -1, -1);
  int hv[4] = {h4.x, h4.y, h4.z, h4.w};
  int gv[4], lp[4];
  int2 n0[4];
  #pragma unroll
  for (int s = 0; s < 4; ++s) {
    lp[s] = -1;
    if (hv[s] < 0) { gv[s] = ZROW; }
    else {
      n0[s] = node[hv[s]];                      // scattered 8B read
      if (n0[s].x < 0) gv[s] = n0[s].y;         // single input
      else             lp[s] = atomicAdd(&l_cnt, 1);
    }
  }
  __syncthreads();
  if (t == 0) l_base = (l_cnt > 0) ? atomicAdd(&ctrs[0], l_cnt) : 0;
  __syncthreads();
  #pragma unroll
  for (int s = 0; s < 4; ++s) {
    if (lp[s] >= 0) {
      int pos = l_base + lp[s];
      if (pos < AUXCAP) { list[pos] = hv[s]; gv[s] = N_VOX + pos; }
      else              { gv[s] = n0[s].y; }    // statistical impossibility guard
    }
  }
  if (ok) {
    int b0 = w * 4;
    int k  = b0 / NPAD;                         // 4 consecutive b share k (NPAD%4==0)
    int o0 = b0 - k * NPAD;
    #pragma unroll
    for (int s = 0; s < 4; ++s) bt[(size_t)(o0 + s) * K3 + k] = gv[s];
  }
}

// ---- fixup: aux row = sum of chain's input rows (bf16 in, f32 acc) ----------
__global__ __launch_bounds__(256) void fixup_kernel(short* __restrict__ xb,
                                                    const int* __restrict__ list,
                                                    const int2* __restrict__ node,
                                                    const int* __restrict__ ctrs) {
  int n = ctrs[0]; if (n > AUXCAP) n = AUXCAP;
  int wid  = (blockIdx.x * 256 + threadIdx.x) >> 6;
  int lane = threadIdx.x & 63;
  int nw   = gridDim.x * 4;
  for (int i = wid; i < n; i += nw) {
    int h = list[i];
    float acc = 0.f;
    while (h >= 0) {
      int2 nd = node[h];                        // wave-uniform broadcast
      acc += bf2f(xb[(size_t)nd.y * 64 + lane]);
      h = nd.x;
    }
    xb[(size_t)(N_VOX + i) * 64 + lane] = f2bf(acc);
  }
}

// ---- conv: 64 rows/block (16/wave); per k: 1 row-gather set + 8 MFMA;
//      depth-2 row prefetch; idx from bt[o][27] (L1-hot); W[k] LDS dbuf +
//      XOR-swizzle; fused BN stats.  launch_bounds(256,6): 6 blocks/CU --------
// A lane l: row=l&15, k-slots (l>>4)*8+j (+32);  B lane l: col=l&15, same slots.
// C/D: col=lane&15, row=(lane>>4)*4+reg  [rounds 1-6 proven].
// LDS swizzle: logical byte ^= ((row c)&7)<<4   [rounds 5-6 proven, 0 conflicts].
__global__ __launch_bounds__(256, 6) void conv_out_kernel(const short* __restrict__ xb,
                                                          const short* __restrict__ wt,
                                                          const int* __restrict__ bt,
                                                          float* __restrict__ out,
                                                          float* __restrict__ stats) {
  __shared__ short lds[2 * 4096];               // 2 x 8 KB W double buffer
  __shared__ float ls[128];
  int t = threadIdx.x, wave = t >> 6, lane = t & 63;
  int g = lane >> 4, c0 = lane & 15, g8 = g * 8;
  int o = blockIdx.x * 64 + wave * 16 + c0;
  const int* bo = bt + (size_t)o * K3;          // 27 idx in 2 cache lines

  int rb  = ((c0 * 128 + g * 16) ^ ((c0 & 7) << 4)) >> 1;
  int wb0 = ((t * 32) ^ (((t >> 2) & 7) << 4)) >> 1;
  if (t < 128) ls[t] = 0.f;

  f32x4 acc[4];
  #pragma unroll
  for (int n = 0; n < 4; ++n) { acc[n][0]=0.f; acc[n][1]=0.f; acc[n][2]=0.f; acc[n][3]=0.f; }

  // prologue: stage W0; gather rows k=0 (cur) and k=1 (next)
  bf16x8 s0w = *(const bf16x8*)(wt + t * 16);
  bf16x8 s1w = *(const bf16x8*)(wt + t * 16 + 8);
  int i0 = bo[0];
  const short* xr0 = xb + (size_t)i0 * 64;
  bf16x8 a0c = *(const bf16x8*)(xr0 + g8);
  bf16x8 a1c = *(const bf16x8*)(xr0 + 32 + g8);
  int i1 = bo[1];
  const short* xr1 = xb + (size_t)i1 * 64;
  bf16x8 a0n = *(const bf16x8*)(xr1 + g8);
  bf16x8 a1n = *(const bf16x8*)(xr1 + 32 + g8);
  *(bf16x8*)&lds[wb0]     = s0w;
  *(bf16x8*)&lds[wb0 ^ 8] = s1w;
  __syncthreads();

  int buf = 0;
  for (int k = 0; k < K3; ++k) {
    if (k + 1 < K3) {                           // W stage loads for k+1
      const short* wn = wt + (size_t)(k + 1) * 4096 + t * 16;
      s0w = *(const bf16x8*)(wn);
      s1w = *(const bf16x8*)(wn + 8);
    }
    // issue gather for k+2 (depth-2; idx read is L1-hot)
    int i2 = (k + 2 < K3) ? bo[k + 2] : ZROW;
    const short* xr2 = xb + (size_t)i2 * 64;
    bf16x8 a0m = *(const bf16x8*)(xr2 + g8);
    bf16x8 a1m = *(const bf16x8*)(xr2 + 32 + g8);

    // compute k from lds[buf]
    const short* lb = lds + buf * 4096;
    #pragma unroll
    for (int n = 0; n < 4; ++n) {
      bf16x8 b0 = *(const bf16x8*)&lb[rb + n * 1024];
      bf16x8 b1 = *(const bf16x8*)&lb[(rb ^ 32) + n * 1024];
      acc[n] = __builtin_amdgcn_mfma_f32_16x16x32_bf16(a0c, b0, acc[n], 0, 0, 0);
      acc[n] = __builtin_amdgcn_mfma_f32_16x16x32_bf16(a1c, b1, acc[n], 0, 0, 0);
    }
    if (k + 1 < K3) {                           // publish W k+1
      short* wd = lds + (buf ^ 1) * 4096;
      *(bf16x8*)&wd[wb0]     = s0w;
      *(bf16x8*)&wd[wb0 ^ 8] = s1w;
    }
    __syncthreads();
    a0c = a0n; a1c = a1n; a0n = a0m; a1n = a1m; buf ^= 1;
  }

  // store: each out row exactly once
  int orow = blockIdx.x * 64 + wave * 16 + (g << 2);
  #pragma unroll
  for (int j = 0; j < 4; ++j) {
    int r = orow + j;
    if (r < N_VOX) {
      float* op = out + (size_t)r * 64 + c0;
      op[0]  = acc[0][j];
      op[16] = acc[1][j];
      op[32] = acc[2][j];
      op[48] = acc[3][j];
    }
  }

  // fused BN stats (padding rows are exact zeros -> contribute nothing)
  #pragma unroll
  for (int n = 0; n < 4; ++n) {
    float s = 0.f, q = 0.f;
    #pragma unroll
    for (int j = 0; j < 4; ++j) { float v = acc[n][j]; s += v; q += v * v; }
    atomicAdd(&ls[n * 16 + c0], s);
    atomicAdd(&ls[64 + n * 16 + c0], q);
  }
  __syncthreads();
  if (t < 128) unsafeAtomicAdd(&stats[t], ls[t]);
}

// ---- finalize BN + ReLU in place -------------------------------------------
__global__ __launch_bounds__(256) void norm_kernel(float* __restrict__ out,
                                                   const float* __restrict__ stats,
                                                   const float* __restrict__ gamma,
                                                   const float* __restrict__ beta) {
  int i4 = blockIdx.x * 256 + threadIdx.x;
  if (i4 >= N_VOX * 16) return;
  const float invN = 1.0f / (float)N_VOX;
  float4 v = ((const float4*)out)[i4];
  int c0 = (i4 << 2) & 63;
  float r[4] = {v.x, v.y, v.z, v.w};
  #pragma unroll
  for (int j = 0; j < 4; ++j) {
    int c = c0 + j;
    float mean = stats[c] * invN;
    float ex2  = stats[64 + c] * invN;
    float var  = ex2 - mean * mean;
    float scale = gamma[c] * rsqrtf(var + BN_EPS);
    float shift = beta[c] - mean * scale;
    r[j] = fmaxf(r[j] * scale + shift, 0.0f);
  }
  v.x = r[0]; v.y = r[1]; v.z = r[2]; v.w = r[3];
  ((float4*)out)[i4] = v;
}

extern "C" void kernel_launch(void* const* d_in, const int* in_sizes, int n_in,
                              void* d_out, int out_size, void* d_ws, size_t ws_size,
                              hipStream_t stream) {
  const float* x      = (const float*)d_in[0];
  const float* W      = (const float*)d_in[1];
  const float* gamma  = (const float*)d_in[2];
  const float* beta   = (const float*)d_in[3];
  const int*   in_idx = (const int*)d_in[4];
  const int*   out_idx= (const int*)d_in[5];
  float* out = (float*)d_out;

  char* ws = (char*)d_ws;
  short* wt    = (short*)(ws + OFF_WT);
  float* stats = (float*)(ws + OFF_STATS);
  int*   ctrs  = (int*)(ws + OFF_CTRS);
  int*   bt    = (int*)(ws + OFF_BT);
  int2*  node  = (int2*)(ws + OFF_NODE);
  int*   list  = (int*)(ws + OFF_LIST);
  short* xb    = (short*)(ws + OFF_XB);
  int*   bh    = (int*)(ws + OFF_BH);           // aliased into xb aux region

  hipMemsetAsync(ws + OFF_STATS, 0, OFF_BT - OFF_STATS, stream);    // stats+ctrs
  hipMemsetAsync((void*)bh, 0xFF, (size_t)NBINS * 4, stream);       // heads = -1

  init_build_kernel<<<GRID_IB, 256, 0, stream>>>(W, x, in_idx, out_idx,
                                                 wt, xb, bh, node);
  compact_kernel<<<(NBINS / 4 + 255) / 256, 256, 0, stream>>>(bh, node, bt, list, ctrs);
  fixup_kernel<<<4096, 256, 0, stream>>>(xb, list, node, ctrs);
  conv_out_kernel<<<NPAD / 64, 256, 0, stream>>>(xb, wt, bt, out, stats);
  norm_kernel<<<(N_VOX * 16 + 255) / 256, 256, 0, stream>>>(out, stats, gamma, beta);
}

// Round 8
// 216.345 us; speedup vs baseline: 1.1831x; 1.1831x over previous
//
#include <hip/hip_runtime.h>

// Sparse conv block, output-major, exch-chain inversion (round 8):
//   init+build (fused): bf16 prep + per-pair atomicExch chain heads
//   compact: chain depth-2 walk -> bg2[k][o] = {in0|aux|ZROW, in1|ZROW}
//            (cnt<=2 consumed inline by conv; cnt>=3 -> aux pre-sum slot)
//   fixup: aux rows (cnt>=3 only, ~21k) = bf16 sum of full chain
//   conv: 128 rows/block (round-6 proven shape), DUAL-input gather + 32 MFMA
//         per k-iter, W[k] LDS double-buffered + XOR-swizzled, fused BN stats
//   norm: BN+ReLU.                                MI355X / gfx950.

#define N_VOX   100000
#define NPAD    100096                  // multiple of 64
#define K3      27
#define M_PAIRS 40000
#define NPAIRS  (K3 * M_PAIRS)          // 1,080,000
#define BN_EPS  1e-5f
#define NBINS   (K3 * NPAD)             // 2,702,592
#define AUXMAX  49152                   // E[cnt>=3 bins] = 21.4k, big headroom
#define AUXCAP  (AUXMAX - 1)
#define ZROW    (N_VOX + AUXMAX - 1)    // zeroed gather row (empty slots)

// ---- workspace layout (bytes), total 60,580,928 (< proven-fit 64,903,232) ---
#define OFF_WT     0u                       // bf16 Wt[k][c][i]        221,184
#define OFF_STATS  221184u                  // f32[128]
#define OFF_CTRS   221696u                  // [0]=aux counter
#define OFF_BG2    221760u                  // int2 bg2[NBINS]      21,620,736
#define OFF_NODE   21842496u                // int2 node[NPAIRS]     8,640,000
#define OFF_LIST   30482496u                // int list[AUXMAX]        196,608
#define OFF_XB     30679104u                // bf16 rows[N_VOX+AUXMAX][64] 19,091,456
#define OFF_BH     49770560u                // int bh[NBINS]        10,810,368

#define NB_WT    432                    // 27*4096/256
#define NB_XB    3125                   // ceil(N_VOX*8/256)
#define NB_BUILD 4219                   // ceil(NPAIRS/256)
#define GRID_IB  (NB_WT + NB_XB + 1 + NB_BUILD)   // 7777

typedef __attribute__((ext_vector_type(8))) short bf16x8;
typedef __attribute__((ext_vector_type(4))) float f32x4;

__device__ __forceinline__ short f2bf(float f) {
  unsigned u = __builtin_bit_cast(unsigned, f);
  u += 0x7FFFu + ((u >> 16) & 1u);
  return (short)(u >> 16);
}
__device__ __forceinline__ float bf2f(short s) {
  unsigned u = ((unsigned)(unsigned short)s) << 16;
  return __builtin_bit_cast(float, u);
}

// ---- fused init + build -----------------------------------------------------
__global__ __launch_bounds__(256) void init_build_kernel(const float* __restrict__ W,
                                                         const float* __restrict__ x,
                                                         const int* __restrict__ in_idx,
                                                         const int* __restrict__ out_idx,
                                                         short* __restrict__ wt,
                                                         short* __restrict__ xb,
                                                         int* __restrict__ bh,
                                                         int2* __restrict__ node) {
  int b = blockIdx.x, t = threadIdx.x;
  if (b < NB_WT) {
    int id = b * 256 + t;
    int k = id >> 12, rem = id & 4095, c = rem >> 6, i = rem & 63;
    wt[id] = f2bf(W[(k << 12) + (i << 6) + c]);     // wt[k][c][i]
  } else if (b < NB_WT + NB_XB) {
    int id = (b - NB_WT) * 256 + t;
    if (id < N_VOX * 8) {
      float4 lo = ((const float4*)x)[id * 2];
      float4 hi = ((const float4*)x)[id * 2 + 1];
      bf16x8 v;
      v[0] = f2bf(lo.x); v[1] = f2bf(lo.y); v[2] = f2bf(lo.z); v[3] = f2bf(lo.w);
      v[4] = f2bf(hi.x); v[5] = f2bf(hi.y); v[6] = f2bf(hi.z); v[7] = f2bf(hi.w);
      ((bf16x8*)xb)[id] = v;
    }
  } else if (b == NB_WT + NB_XB) {
    if (t < 8) {
      bf16x8 z = {0, 0, 0, 0, 0, 0, 0, 0};
      ((bf16x8*)(xb + (size_t)ZROW * 64))[t] = z;
    }
  } else {
    int id = (b - (NB_WT + NB_XB + 1)) * 256 + t;
    if (id < NPAIRS) {
      int k  = id / M_PAIRS;
      int in = in_idx[id];
      int o  = out_idx[id];
      int bb = k * NPAD + o;
      int old = atomicExch(&bh[bb], id);
      node[id] = make_int2(old, in);
    }
  }
}

// ---- compact: depth-2 chain walk -> bg2 = {g0, g1}; cnt>=3 -> aux slot ------
__global__ __launch_bounds__(256) void compact_kernel(const int* __restrict__ bh,
                                                      const int2* __restrict__ node,
                                                      int2* __restrict__ bg2,
                                                      int* __restrict__ list,
                                                      int* __restrict__ ctrs) {
  __shared__ int l_cnt, l_base;
  int t = threadIdx.x;
  if (t == 0) l_cnt = 0;
  __syncthreads();
  int w = blockIdx.x * 256 + t;                 // 4 bins per thread
  bool ok = (w < NBINS / 4);
  int4 h4 = ok ? ((const int4*)bh)[w] : make_int4(-1, -1, -1, -1);
  int hv[4] = {h4.x, h4.y, h4.z, h4.w};
  int g0[4], g1[4], lp[4];
  #pragma unroll
  for (int s = 0; s < 4; ++s) {
    lp[s] = -1; g0[s] = ZROW; g1[s] = ZROW;
    if (hv[s] >= 0) {
      int2 n0 = node[hv[s]];                    // scattered 8B read
      g0[s] = n0.y;
      if (n0.x >= 0) {
        int2 n1 = node[n0.x];                   // second scattered read (cnt>=2)
        g1[s] = n1.y;
        if (n1.x >= 0) lp[s] = atomicAdd(&l_cnt, 1);   // cnt>=3 -> aux
      }
    }
  }
  __syncthreads();
  if (t == 0) l_base = (l_cnt > 0) ? atomicAdd(&ctrs[0], l_cnt) : 0;
  __syncthreads();
  #pragma unroll
  for (int s = 0; s < 4; ++s) {
    if (lp[s] >= 0) {
      int pos = l_base + lp[s];
      if (pos < AUXCAP) { list[pos] = hv[s]; g0[s] = N_VOX + pos; g1[s] = ZROW; }
      // else: impossible-overflow guard keeps {in_head, in_next} (approx)
    }
  }
  if (ok) {                                     // coalesced int4 x2 write
    ((int4*)bg2)[w * 2]     = make_int4(g0[0], g1[0], g0[1], g1[1]);
    ((int4*)bg2)[w * 2 + 1] = make_int4(g0[2], g1[2], g0[3], g1[3]);
  }
}

// ---- fixup: aux row = f32 sum of full chain's input rows (cnt>=3 only) ------
__global__ __launch_bounds__(256) void fixup_kernel(short* __restrict__ xb,
                                                    const int* __restrict__ list,
                                                    const int2* __restrict__ node,
                                                    const int* __restrict__ ctrs) {
  int n = ctrs[0]; if (n > AUXCAP) n = AUXCAP;
  int wid  = (blockIdx.x * 256 + threadIdx.x) >> 6;
  int lane = threadIdx.x & 63;
  int nw   = gridDim.x * 4;
  for (int i = wid; i < n; i += nw) {
    int h = list[i];
    float acc = 0.f;
    while (h >= 0) {
      int2 nd = node[h];                        // wave-uniform broadcast
      acc += bf2f(xb[(size_t)nd.y * 64 + lane]);
      h = nd.x;
    }
    xb[(size_t)(N_VOX + i) * 64 + lane] = f2bf(acc);
  }
}

// ---- conv: 128 rows/block (32/wave, round-6 proven); per k per wave:
//      DUAL-input gathers (8 frag loads) + 32 MFMA; W[k] LDS dbuf + XOR
//      swizzle; depth-1 row prefetch, depth-2 idx; fused BN stats ------------
// A lane l: row=l&15, k-slots (l>>4)*8+j (+32);  B lane l: col=l&15, same slots.
// C/D: col=lane&15, row=(lane>>4)*4+reg  [rounds 1-7 proven].
// LDS swizzle: logical byte ^= ((row c)&7)<<4   [rounds 5-7 proven].
#define LOADROW(d0, d1, idx)                                    \
  { const short* _p = xb + (size_t)(idx) * 64;                  \
    d0 = *(const bf16x8*)(_p + g8);                             \
    d1 = *(const bf16x8*)(_p + 32 + g8); }

__global__ __launch_bounds__(256) void conv_out_kernel(const short* __restrict__ xb,
                                                       const short* __restrict__ wt,
                                                       const int2* __restrict__ bg,
                                                       float* __restrict__ out,
                                                       float* __restrict__ stats) {
  __shared__ short lds[2 * 4096];               // 2 x 8 KB W double buffer
  __shared__ float ls[128];
  int t = threadIdx.x, wave = t >> 6, lane = t & 63;
  int g = lane >> 4, c0 = lane & 15, g8 = g * 8;
  int o0 = blockIdx.x * 128 + wave * 32 + c0;   // rows 0..15 of this wave
  int o1 = o0 + 16;                             // rows 16..31

  int rb  = ((c0 * 128 + g * 16) ^ ((c0 & 7) << 4)) >> 1;
  int wb0 = ((t * 32) ^ (((t >> 2) & 7) << 4)) >> 1;
  if (t < 128) ls[t] = 0.f;

  f32x4 acc0[4], acc1[4];
  #pragma unroll
  for (int n = 0; n < 4; ++n) {
    acc0[n][0]=0.f; acc0[n][1]=0.f; acc0[n][2]=0.f; acc0[n][3]=0.f;
    acc1[n][0]=0.f; acc1[n][1]=0.f; acc1[n][2]=0.f; acc1[n][3]=0.f;
  }

  // prologue: stage W0; gather k=0 rows (both inputs); idx for k=1
  bf16x8 s0w = *(const bf16x8*)(wt + t * 16);
  bf16x8 s1w = *(const bf16x8*)(wt + t * 16 + 8);
  int2 gac = bg[o0], gbc = bg[o1];
  bf16x8 ap0c, ap1c, as0c, as1c, bp0c, bp1c, bs0c, bs1c;
  LOADROW(ap0c, ap1c, gac.x); LOADROW(as0c, as1c, gac.y);
  LOADROW(bp0c, bp1c, gbc.x); LOADROW(bs0c, bs1c, gbc.y);
  int2 gan = bg[NPAD + o0], gbn = bg[NPAD + o1];
  *(bf16x8*)&lds[wb0]     = s0w;
  *(bf16x8*)&lds[wb0 ^ 8] = s1w;
  __syncthreads();

  int buf = 0;
  for (int k = 0; k < K3; ++k) {
    if (k + 1 < K3) {                           // W stage loads for k+1
      const short* wn = wt + (size_t)(k + 1) * 4096 + t * 16;
      s0w = *(const bf16x8*)(wn);
      s1w = *(const bf16x8*)(wn + 8);
    }
    // gather rows for k+1 (branchless; empty slots -> ZROW, L1-hot)
    bf16x8 ap0n, ap1n, as0n, as1n, bp0n, bp1n, bs0n, bs1n;
    LOADROW(ap0n, ap1n, gan.x); LOADROW(as0n, as1n, gan.y);
    LOADROW(bp0n, bp1n, gbn.x); LOADROW(bs0n, bs1n, gbn.y);
    int2 gann = make_int2(ZROW, ZROW), gbnn = make_int2(ZROW, ZROW);
    if (k + 2 < K3) {
      gann = bg[(size_t)(k + 2) * NPAD + o0];
      gbnn = bg[(size_t)(k + 2) * NPAD + o1];
    }
    // compute k from lds[buf]
    const short* lb = lds + buf * 4096;
    #pragma unroll
    for (int n = 0; n < 4; ++n) {
      bf16x8 b0 = *(const bf16x8*)&lb[rb + n * 1024];
      bf16x8 b1 = *(const bf16x8*)&lb[(rb ^ 32) + n * 1024];
      acc0[n] = __builtin_amdgcn_mfma_f32_16x16x32_bf16(ap0c, b0, acc0[n], 0, 0, 0);
      acc0[n] = __builtin_amdgcn_mfma_f32_16x16x32_bf16(ap1c, b1, acc0[n], 0, 0, 0);
      acc0[n] = __builtin_amdgcn_mfma_f32_16x16x32_bf16(as0c, b0, acc0[n], 0, 0, 0);
      acc0[n] = __builtin_amdgcn_mfma_f32_16x16x32_bf16(as1c, b1, acc0[n], 0, 0, 0);
      acc1[n] = __builtin_amdgcn_mfma_f32_16x16x32_bf16(bp0c, b0, acc1[n], 0, 0, 0);
      acc1[n] = __builtin_amdgcn_mfma_f32_16x16x32_bf16(bp1c, b1, acc1[n], 0, 0, 0);
      acc1[n] = __builtin_amdgcn_mfma_f32_16x16x32_bf16(bs0c, b0, acc1[n], 0, 0, 0);
      acc1[n] = __builtin_amdgcn_mfma_f32_16x16x32_bf16(bs1c, b1, acc1[n], 0, 0, 0);
    }
    if (k + 1 < K3) {                           // publish W k+1
      short* wd = lds + (buf ^ 1) * 4096;
      *(bf16x8*)&wd[wb0]     = s0w;
      *(bf16x8*)&wd[wb0 ^ 8] = s1w;
    }
    __syncthreads();
    ap0c = ap0n; ap1c = ap1n; as0c = as0n; as1c = as1n;
    bp0c = bp0n; bp1c = bp1n; bs0c = bs0n; bs1c = bs1n;
    gan = gann; gbn = gbnn; buf ^= 1;
  }

  // store: each out row exactly once
  int orow = blockIdx.x * 128 + wave * 32 + (g << 2);
  #pragma unroll
  for (int j = 0; j < 4; ++j) {
    int r0 = orow + j, r1 = orow + 16 + j;
    if (r0 < N_VOX) {
      float* op = out + (size_t)r0 * 64 + c0;
      op[0] = acc0[0][j]; op[16] = acc0[1][j]; op[32] = acc0[2][j]; op[48] = acc0[3][j];
    }
    if (r1 < N_VOX) {
      float* op = out + (size_t)r1 * 64 + c0;
      op[0] = acc1[0][j]; op[16] = acc1[1][j]; op[32] = acc1[2][j]; op[48] = acc1[3][j];
    }
  }

  // fused BN stats (padding rows hold exact zeros -> contribute nothing)
  #pragma unroll
  for (int n = 0; n < 4; ++n) {
    float s = 0.f, q = 0.f;
    #pragma unroll
    for (int j = 0; j < 4; ++j) {
      float v0 = acc0[n][j], v1 = acc1[n][j];
      s += v0 + v1; q += v0 * v0 + v1 * v1;
    }
    atomicAdd(&ls[n * 16 + c0], s);
    atomicAdd(&ls[64 + n * 16 + c0], q);
  }
  __syncthreads();
  if (t < 128) unsafeAtomicAdd(&stats[t], ls[t]);
}

// ---- finalize BN + ReLU in place -------------------------------------------
__global__ __launch_bounds__(256) void norm_kernel(float* __restrict__ out,
                                                   const float* __restrict__ stats,
                                                   const float* __restrict__ gamma,
                                                   const float* __restrict__ beta) {
  int i4 = blockIdx.x * 256 + threadIdx.x;
  if (i4 >= N_VOX * 16) return;
  const float invN = 1.0f / (float)N_VOX;
  float4 v = ((const float4*)out)[i4];
  int c0 = (i4 << 2) & 63;
  float r[4] = {v.x, v.y, v.z, v.w};
  #pragma unroll
  for (int j = 0; j < 4; ++j) {
    int c = c0 + j;
    float mean = stats[c] * invN;
    float ex2  = stats[64 + c] * invN;
    float var  = ex2 - mean * mean;
    float scale = gamma[c] * rsqrtf(var + BN_EPS);
    float shift = beta[c] - mean * scale;
    r[j] = fmaxf(r[j] * scale + shift, 0.0f);
  }
  v.x = r[0]; v.y = r[1]; v.z = r[2]; v.w = r[3];
  ((float4*)out)[i4] = v;
}

extern "C" void kernel_launch(void* const* d_in, const int* in_sizes, int n_in,
                              void* d_out, int out_size, void* d_ws, size_t ws_size,
                              hipStream_t stream) {
  const float* x      = (const float*)d_in[0];
  const float* W      = (const float*)d_in[1];
  const float* gamma  = (const float*)d_in[2];
  const float* beta   = (const float*)d_in[3];
  const int*   in_idx = (const int*)d_in[4];
  const int*   out_idx= (const int*)d_in[5];
  float* out = (float*)d_out;

  char* ws = (char*)d_ws;
  short* wt    = (short*)(ws + OFF_WT);
  float* stats = (float*)(ws + OFF_STATS);
  int*   ctrs  = (int*)(ws + OFF_CTRS);
  int2*  bg2   = (int2*)(ws + OFF_BG2);
  int2*  node  = (int2*)(ws + OFF_NODE);
  int*   list  = (int*)(ws + OFF_LIST);
  short* xb    = (short*)(ws + OFF_XB);
  int*   bh    = (int*)(ws + OFF_BH);

  hipMemsetAsync(ws + OFF_STATS, 0, OFF_BG2 - OFF_STATS, stream);   // stats+ctrs
  hipMemsetAsync((void*)bh, 0xFF, (size_t)NBINS * 4, stream);       // heads = -1

  init_build_kernel<<<GRID_IB, 256, 0, stream>>>(W, x, in_idx, out_idx,
                                                 wt, xb, bh, node);
  compact_kernel<<<(NBINS / 4 + 255) / 256, 256, 0, stream>>>(bh, node, bg2, list, ctrs);
  fixup_kernel<<<1024, 256, 0, stream>>>(xb, list, node, ctrs);
  conv_out_kernel<<<NPAD / 128, 256, 0, stream>>>(xb, wt, bg2, out, stats);
  norm_kernel<<<(N_VOX * 16 + 255) / 256, 256, 0, stream>>>(out, stats, gamma, beta);
}